// Round 10
// baseline (7750.518 us; speedup 1.0000x reference)
//
#include <hip/hip_runtime.h>
#include <stdint.h>

#define BATCHES 32
#define NPT     100000
#define NSAMP   1024
#define GPB     16         // groups (blocks) per batch
#define NPAIR   16         // batch pairs; block serves batches (p, p+16)
#define TPB     1024       // 16 waves: 0..14 compute (960 thr), 15 = sync wave
#define NCW     15         // compute waves
#define CTH     (NCW*64)   // 960 compute threads
#define PPB     6250       // points per (batch, group)
#define PPT     7          // ceil(6250/960): k<6 full (5760), k==6 ct<490
#define TAILT   490

typedef unsigned long long u64;
typedef unsigned int u32;

// Mailbox rec[tag&1][batch][group][4 u64] — self-validating tagged words.
// tag2(v) = ((v>>1)+1)&3 in bits [63:62] of every word; within a slot only
// versions v / v+2 are observable and their tag2 differ; memset-0 invalid
// for the first expected tag.
//   w0 = tag2 | key[61:0]
//   w1 = tag2 | key[63:62]<<60 | x<<28 | y>>4
//   w2 = tag2 | (y&0xF)<<58   | z<<26 | idx<<9     (idx: 17 bits)
//   w3 = pad (keeps 16B-pair alignment for the sync wave's paired loads)
#define WS_BYTES (2 * BATCHES * GPB * 4 * 8)   // 32 KB

__device__ __forceinline__ void red_ki(u64& key, u32& idx, int off) {
    u64 ok = __shfl_xor(key, off, 64);
    u32 oi = __shfl_xor(idx, off, 64);
    if (ok > key || (ok == key && oi < idx)) { key = ok; idx = oi; }
}

__device__ __forceinline__ void red_step(u64& key, u32& idx, float& x, float& y, float& z, int off) {
    u64   ok = __shfl_xor(key, off, 64);
    u32   oi = __shfl_xor(idx, off, 64);
    float ox = __shfl_xor(x, off, 64);
    float oy = __shfl_xor(y, off, 64);
    float oz = __shfl_xor(z, off, 64);
    if (ok > key || (ok == key && oi < idx)) { key = ok; idx = oi; x = ox; y = oy; z = oz; }
}

__global__ void
__attribute__((amdgpu_flat_work_group_size(TPB, TPB), amdgpu_waves_per_eu(4, 4)))
fps_kernel(const float* __restrict__ coord,
           const int* __restrict__ seed_raw,
           float* __restrict__ out,
           u64* __restrict__ rec)
{
    const int tid  = threadIdx.x;
    const int lane = tid & 63;
    const int wid  = tid >> 6;
    const int p    = (int)blockIdx.x & (NPAIR - 1);   // pair id
    const int g    = (int)blockIdx.x >> 4;            // group 0..15
    const int base = g * PPB;
    const int bA = p, bB = p + NPAIR;

    // Winner words per (batch-slot, parity): tag2-versioned like rec.
    //   v0 = tag2 | x<<30 | y>>2
    //   v1 = tag2 | (y&3)<<60 | z<<28 | idx<<11
    __shared__ u64 winw[2][2][2];   // [xb][t&1][word]
    __shared__ u32 sbar[8];         // rolling soft-barrier counters (monotone)
    __shared__ u64   pkey[2][NCW];  // wave partials, double-buffered by phase
    __shared__ u32   pidx[2][NCW];
    __shared__ float pxs[2][NCW], pys[2][NCW], pzs[2][NCW];

    if (tid < 8) { sbar[tid] = 0; ((u64*)winw)[tid] = 0ull; }
    __syncthreads();   // only block-wide barrier (before wave-role split)

    float* cent_out = out;                       // (B, 1024) as float
    float* samp_out = out + BATCHES * NSAMP;     // (B, 1024, 3)

    if (wid == NCW) {
        // ------- SYNC WAVE: dual-batch concurrent poll -> LDS delivery -----
        for (int t = 1; t < NSAMP; ++t) {
            const u64 t2 = (u64)(((t >> 1) + 1) & 3);
            // Pair-load: lane i<32 covers u64s [2i,2i+1] of batch A's 64-word
            // region; lanes 32..63 likewise for batch B. Even pair = (w0,w1),
            // odd pair = (w2,pad).
            const size_t regA = ((size_t)((t & 1) * BATCHES + bA) * GPB) * 4;
            const size_t regB = ((size_t)((t & 1) * BATCHES + bB) * GPB) * 4;
            u64* ad = rec + ((lane < 32) ? (regA + 2 * lane) : (regB + 2 * (lane - 32)));
            bool dA = false, dB = false;
            u64 wlo = 0, whi = 0;
            for (;;) {
                wlo = __hip_atomic_load(&ad[0], __ATOMIC_RELAXED, __HIP_MEMORY_SCOPE_AGENT);
                whi = __hip_atomic_load(&ad[1], __ATOMIC_RELAXED, __HIP_MEMORY_SCOPE_AGENT);
                bool ok0 = (wlo >> 62) == t2;
                bool ok1 = (whi >> 62) == t2;
                bool ok  = ((lane & 1) == 0) ? (ok0 && ok1) : ok0;   // odd: w2 only
                u64 bal = __ballot(ok);
                #pragma unroll
                for (int xb = 0; xb < 2; ++xb) {
                    bool done = xb ? dB : dA;
                    u64 msk = xb ? 0xFFFFFFFF00000000ull : 0x00000000FFFFFFFFull;
                    if (!done && (bal & msk) == msk) {
                        const int srcBase = xb ? 32 : 0;
                        // Gather record j (j = lane < 16): w0,w1 from lane
                        // srcBase+2j; w2 from lane srcBase+2j+1 (lo word).
                        int sj = srcBase + 2 * (lane & 15);
                        u64 w0 = __shfl(wlo, sj, 64);
                        u64 w1 = __shfl(whi, sj, 64);
                        u64 w2 = __shfl(wlo, sj + 1, 64);
                        u64 k3 = 0ull; u32 i3 = 0xFFFFFFFFu; float x3 = 0.f, y3 = 0.f, z3 = 0.f;
                        if (lane < GPB) {
                            k3 = (w0 & 0x3FFFFFFFFFFFFFFFull) | (((w1 >> 60) & 3ull) << 62);
                            u32 xbt = (u32)(w1 >> 28);
                            u32 ybt = (u32)(((w1 & 0xFFFFFFFull) << 4) | ((w2 >> 58) & 0xFull));
                            u32 zbt = (u32)(w2 >> 26);
                            i3 = (u32)((w2 >> 9) & 0x1FFFFu);
                            x3 = __uint_as_float(xbt); y3 = __uint_as_float(ybt); z3 = __uint_as_float(zbt);
                        }
                        red_step(k3, i3, x3, y3, z3, 8); red_step(k3, i3, x3, y3, z3, 4);
                        red_step(k3, i3, x3, y3, z3, 2); red_step(k3, i3, x3, y3, z3, 1);
                        if (lane == 0) {
                            u32 xbt = __float_as_uint(x3), ybt = __float_as_uint(y3), zbt = __float_as_uint(z3);
                            u64 v0 = (t2 << 62) | ((u64)xbt << 30) | (u64)(ybt >> 2);
                            u64 v1 = (t2 << 62) | ((u64)(ybt & 3u) << 60) | ((u64)zbt << 28) | ((u64)i3 << 11);
                            __hip_atomic_store(&winw[xb][t & 1][0], v0, __ATOMIC_RELAXED, __HIP_MEMORY_SCOPE_WORKGROUP);
                            __hip_atomic_store(&winw[xb][t & 1][1], v1, __ATOMIC_RELAXED, __HIP_MEMORY_SCOPE_WORKGROUP);
                        }
                        if (xb) dB = true; else dA = true;
                    }
                }
                if (dA && dB) break;
                __builtin_amdgcn_s_sleep(1);
            }
        }
        return;
    }

    // ---------------- COMPUTE WAVES (0..14) --------------------------------
    const int ct = tid;   // 0..959
    const float* cbA = coord + (size_t)bA * (NPT * 3);
    const float* cbB = coord + (size_t)bB * (NPT * 3);

    // Seed indices (robust to int32 / int64 farthest_init materialization).
    int odd = 0;
    #pragma unroll
    for (int i = 1; i < 32; i += 2) odd |= seed_raw[i];
    u32 scur[2]; float scx[2], scy[2], scz[2];
    scur[0] = (u32)((odd == 0) ? seed_raw[2 * bA] : seed_raw[bA]);
    scur[1] = (u32)((odd == 0) ? seed_raw[2 * bB] : seed_raw[bB]);
    scx[0] = cbA[(size_t)scur[0] * 3 + 0]; scy[0] = cbA[(size_t)scur[0] * 3 + 1]; scz[0] = cbA[(size_t)scur[0] * 3 + 2];
    scx[1] = cbB[(size_t)scur[1] * 3 + 0]; scy[1] = cbB[(size_t)scur[1] * 3 + 1]; scz[1] = cbB[(size_t)scur[1] * 3 + 2];

    // Coords (2x21 f32) + running f64 min-distance (2x7) in registers
    // (overflow rides the unified AGPR file, not scratch — R6 data).
    float  px[2][PPT], py[2][PPT], pz[2][PPT];
    double d[2][PPT];
    #pragma unroll
    for (int xb = 0; xb < 2; ++xb) {
        const float* cb = xb ? cbB : cbA;
        #pragma unroll
        for (int k = 0; k < PPT; ++k) {
            bool v = (k < PPT - 1) || (ct < TAILT);
            int gi = base + (v ? (k * CTH + ct) : 0);
            px[xb][k] = v ? cb[(size_t)gi * 3 + 0] : 0.f;
            py[xb][k] = v ? cb[(size_t)gi * 3 + 1] : 0.f;
            pz[xb][k] = v ? cb[(size_t)gi * 3 + 2] : 0.f;
            d[xb][k]  = v ? 1.0e10 : 0.0;   // fakes can never win argmax
        }
    }

    for (int t = 0; t < NSAMP; ++t) {
        #pragma unroll
        for (int xb = 0; xb < 2; ++xb) {
            const int batch = xb ? bB : bA;
            const int pi = 2 * t + xb;
            u32 cur; float cx, cy, cz;
            if (t == 0) {
                cur = scur[xb]; cx = scx[xb]; cy = scy[xb]; cz = scz[xb];
            } else {
                const u64 t2 = (u64)(((t >> 1) + 1) & 3);
                u64 v0, v1;
                for (;;) {   // LDS spin — sync wave delivers ahead of need
                    v0 = __hip_atomic_load(&winw[xb][t & 1][0], __ATOMIC_RELAXED, __HIP_MEMORY_SCOPE_WORKGROUP);
                    v1 = __hip_atomic_load(&winw[xb][t & 1][1], __ATOMIC_RELAXED, __HIP_MEMORY_SCOPE_WORKGROUP);
                    if (((v0 >> 62) == t2) & ((v1 >> 62) == t2)) break;
                }
                u32 xbt = (u32)(v0 >> 30);
                u32 ybt = (u32)(((v0 & 0x3FFFFFFFull) << 2) | ((v1 >> 60) & 3ull));
                u32 zbt = (u32)(v1 >> 28);
                cur = (u32)((v1 >> 11) & 0x1FFFFu);
                cx = __uint_as_float(xbt); cy = __uint_as_float(ybt); cz = __uint_as_float(zbt);
            }
            if (g == 0 && wid == 1 && lane == 0) {
                cent_out[batch * NSAMP + t] = (float)cur;
                size_t so = ((size_t)batch * NSAMP + t) * 3;
                samp_out[so + 0] = cx; samp_out[so + 1] = cy; samp_out[so + 2] = cz;
            }
            if (t == NSAMP - 1) continue;   // last emit needs no update/publish

            // Exact f64 update + argmax (bitwise-matches float64 numpy:
            // _rn ops forbid FMA; sum order ((dx^2+dy^2)+dz^2)). Only (bd,bi)
            // tracked in-loop; coords recovered by the winner lane below.
            const double cxd = (double)cx, cyd = (double)cy, czd = (double)cz;
            double bd = -1.0; u32 bi = 0;
            #pragma unroll
            for (int k = 0; k < PPT; ++k) {
                if (k == PPT - 1 && ct >= TAILT) break;
                double dx = __dsub_rn((double)px[xb][k], cxd);
                double dy = __dsub_rn((double)py[xb][k], cyd);
                double dz = __dsub_rn((double)pz[xb][k], czd);
                double d2 = __dadd_rn(__dadd_rn(__dmul_rn(dx, dx), __dmul_rn(dy, dy)),
                                      __dmul_rn(dz, dz));
                double nd = fmin(d[xb][k], d2);
                d[xb][k] = nd;
                bool gt = nd > bd;   // strict > keeps smallest k (= smallest idx)
                bd = gt ? nd : bd;
                bi = gt ? (u32)(base + k * CTH + ct) : bi;
            }
            u64 key = (u64)__double_as_longlong(bd);

            // Lean wave butterfly; unique winner lane recovers its coords.
            u64 wk = key; u32 wi = bi;
            red_ki(wk, wi, 32); red_ki(wk, wi, 16); red_ki(wk, wi, 8);
            red_ki(wk, wi, 4);  red_ki(wk, wi, 2);  red_ki(wk, wi, 1);
            const int pb = pi & 1;
            if (wi == bi) {
                float bx = px[xb][0], by = py[xb][0], bz = pz[xb][0];
                #pragma unroll
                for (int k = 1; k < PPT; ++k) {
                    bool m = (bi == (u32)(base + k * CTH + ct));
                    bx = m ? px[xb][k] : bx;
                    by = m ? py[xb][k] : by;
                    bz = m ? pz[xb][k] : bz;
                }
                pkey[pb][wid] = wk; pidx[pb][wid] = wi;
                pxs[pb][wid] = bx; pys[pb][wid] = by; pzs[pb][wid] = bz;
            }

            // Soft barrier: everyone signals; ONLY wave 0 (the reducer) waits.
            // pkey reuse (distance 2) stays safe: phase pi+2 deposits are gated
            // through consumes that require wave 0's pi-read (see analysis).
            if (lane == 0)
                __hip_atomic_fetch_add(&sbar[pi & 7], 1u, __ATOMIC_RELEASE, __HIP_MEMORY_SCOPE_WORKGROUP);

            if (wid == 0) {
                const u32 tgt = (u32)(NCW * ((pi >> 3) + 1));
                while (__hip_atomic_load(&sbar[pi & 7], __ATOMIC_ACQUIRE, __HIP_MEMORY_SCOPE_WORKGROUP) < tgt) {}
                u64   k2 = (lane < NCW) ? pkey[pb][lane] : 0ull;
                u32   i2 = (lane < NCW) ? pidx[pb][lane] : 0xFFFFFFFFu;
                float x2 = (lane < NCW) ? pxs[pb][lane] : 0.f;
                float y2 = (lane < NCW) ? pys[pb][lane] : 0.f;
                float z2 = (lane < NCW) ? pzs[pb][lane] : 0.f;
                red_step(k2, i2, x2, y2, z2, 8); red_step(k2, i2, x2, y2, z2, 4);
                red_step(k2, i2, x2, y2, z2, 2); red_step(k2, i2, x2, y2, z2, 1);
                if (lane == 0) {
                    const u32 v = (u32)(t + 1);          // tag value
                    const u64 t2p = (u64)(((v >> 1) + 1) & 3);
                    u64* r = rec + ((size_t)((v & 1) * BATCHES + batch) * GPB + g) * 4;
                    u32 xbt = __float_as_uint(x2), ybt = __float_as_uint(y2), zbt = __float_as_uint(z2);
                    u64 w0 = (t2p << 62) | (k2 & 0x3FFFFFFFFFFFFFFFull);
                    u64 w1 = (t2p << 62) | ((k2 >> 62) << 60) | ((u64)xbt << 28) | (u64)(ybt >> 4);
                    u64 w2 = (t2p << 62) | ((u64)(ybt & 0xFu) << 58) | ((u64)zbt << 26) | ((u64)i2 << 9);
                    __hip_atomic_store(&r[0], w0, __ATOMIC_RELAXED, __HIP_MEMORY_SCOPE_AGENT);
                    __hip_atomic_store(&r[1], w1, __ATOMIC_RELAXED, __HIP_MEMORY_SCOPE_AGENT);
                    __hip_atomic_store(&r[2], w2, __ATOMIC_RELAXED, __HIP_MEMORY_SCOPE_AGENT);
                }
            }
        }
    }
}

extern "C" void kernel_launch(void* const* d_in, const int* in_sizes, int n_in,
                              void* d_out, int out_size, void* d_ws, size_t ws_size,
                              hipStream_t stream)
{
    const float* coord = (const float*)d_in[0];
    const int*   seed  = (const int*)d_in[1];
    float* out = (float*)d_out;
    u64* rec = (u64*)d_ws;

    hipMemsetAsync(d_ws, 0, WS_BYTES, stream);
    fps_kernel<<<dim3(NPAIR * GPB), dim3(TPB), 0, stream>>>(coord, seed, out, rec);
}

// Round 11
// 6686.489 us; speedup vs baseline: 1.1591x; 1.1591x over previous
//
#include <hip/hip_runtime.h>
#include <stdint.h>

#define BATCHES 32
#define NPT     100000
#define NSAMP   1024
#define KB      4          // batches per block: q, q+8, q+16, q+24
#define NQUAD   8
#define GPB     32         // groups (blocks) per batch
#define TPB     1024       // waves 0..13 compute, 14 = publisher, 15 = poller
#define NCW     14
#define CTH     (NCW*64)   // 896 compute threads
#define PPB     3125       // points per (batch, group); 32*3125 = 100000
#define PPT     4          // k<3 full (2688), k==3: ct < 437
#define TAILT   437

typedef unsigned long long u64;
typedef unsigned int u32;

// Global mailbox rec[tag&1][batch][group][4 u64] — R7 self-validating words.
// tag2(v) = ((v>>1)+1)&3 in bits [63:62] of every word; within a slot only
// versions v / v+2 are observable (progress gating bounds lead to 2 iters),
// and their tag2 differ; memset-0 is invalid for the first expected tag (=1).
//   w0 = tag2 | key[61:0]
//   w1 = tag2 | key[63:62]<<60 | x<<28 | y>>4
//   w2 = tag2 | (y&0xF)<<58   | z<<26 | idx<<9    (idx: 17 bits)
#define WS_BYTES (2 * BATCHES * GPB * 4 * 8)   // 64 KB

__device__ __forceinline__ void red_ki(u64& key, u32& idx, int off) {
    u64 ok = __shfl_xor(key, off, 64);
    u32 oi = __shfl_xor(idx, off, 64);
    if (ok > key || (ok == key && oi < idx)) { key = ok; idx = oi; }
}

__device__ __forceinline__ void red_step(u64& key, u32& idx, float& x, float& y, float& z, int off) {
    u64   ok = __shfl_xor(key, off, 64);
    u32   oi = __shfl_xor(idx, off, 64);
    float ox = __shfl_xor(x, off, 64);
    float oy = __shfl_xor(y, off, 64);
    float oz = __shfl_xor(z, off, 64);
    if (ok > key || (ok == key && oi < idx)) { key = ok; idx = oi; x = ox; y = oy; z = oz; }
}

__global__ void
__attribute__((amdgpu_flat_work_group_size(TPB, TPB), amdgpu_waves_per_eu(4, 4)))
fps_kernel(const float* __restrict__ coord,
           const int* __restrict__ seed_raw,
           float* __restrict__ out,
           u64* __restrict__ rec)
{
    const int tid  = threadIdx.x;
    const int lane = tid & 63;
    const int wid  = tid >> 6;
    const int q    = (int)blockIdx.x & (NQUAD - 1);
    const int g    = (int)blockIdx.x >> 3;          // 0..31
    const int base = g * PPB;

    // LDS plumbing. pkey 4-deep (pi&3): deposit at pi+4 is gated through
    // consume(t+1) <= publish(pi) <= publisher's read of pkey[pi&3]. sbar
    // 8 rolling monotone counters (reuse distance 8 phases). winw tagged
    // like rec: v0 = tag2|x<<30|y>>2 ; v1 = tag2|(y&3)<<60|z<<28|idx<<11.
    __shared__ u64   winw[KB][2][2];
    __shared__ u32   sbar[8];
    __shared__ u64   pkey[4][NCW];
    __shared__ u32   pidx[4][NCW];
    __shared__ float pxs[4][NCW], pys[4][NCW], pzs[4][NCW];

    if (tid < 8)  sbar[tid] = 0;
    if (tid < KB * 4) ((u64*)winw)[tid] = 0ull;
    __syncthreads();   // only block-wide barrier (before wave-role split)

    float* cent_out = out;                       // (B, 1024) as float
    float* samp_out = out + BATCHES * NSAMP;     // (B, 1024, 3)

    if (wid == NCW) {
        // ---- PUBLISHER WAVE: reduce 14 block partials, publish to mailbox --
        for (int t = 0; t < NSAMP - 1; ++t) {
            #pragma unroll
            for (int xb = 0; xb < KB; ++xb) {
                const int pi = KB * t + xb;
                const u32 tgt = (u32)(NCW * ((pi >> 3) + 1));
                while (__hip_atomic_load(&sbar[pi & 7], __ATOMIC_ACQUIRE, __HIP_MEMORY_SCOPE_WORKGROUP) < tgt) {}
                u64   k2 = (lane < NCW) ? pkey[pi & 3][lane] : 0ull;
                u32   i2 = (lane < NCW) ? pidx[pi & 3][lane] : 0xFFFFFFFFu;
                float x2 = (lane < NCW) ? pxs[pi & 3][lane] : 0.f;
                float y2 = (lane < NCW) ? pys[pi & 3][lane] : 0.f;
                float z2 = (lane < NCW) ? pzs[pi & 3][lane] : 0.f;
                red_step(k2, i2, x2, y2, z2, 8); red_step(k2, i2, x2, y2, z2, 4);
                red_step(k2, i2, x2, y2, z2, 2); red_step(k2, i2, x2, y2, z2, 1);
                if (lane == 0) {
                    const u32 v = (u32)(t + 1);
                    const u64 t2p = (u64)(((v >> 1) + 1) & 3);
                    u64* r = rec + ((size_t)((v & 1) * BATCHES + (q + 8 * xb)) * GPB + g) * 4;
                    u32 xbt = __float_as_uint(x2), ybt = __float_as_uint(y2), zbt = __float_as_uint(z2);
                    u64 w0 = (t2p << 62) | (k2 & 0x3FFFFFFFFFFFFFFFull);
                    u64 w1 = (t2p << 62) | ((k2 >> 62) << 60) | ((u64)xbt << 28) | (u64)(ybt >> 4);
                    u64 w2 = (t2p << 62) | ((u64)(ybt & 0xFu) << 58) | ((u64)zbt << 26) | ((u64)i2 << 9);
                    __hip_atomic_store(&r[0], w0, __ATOMIC_RELAXED, __HIP_MEMORY_SCOPE_AGENT);
                    __hip_atomic_store(&r[1], w1, __ATOMIC_RELAXED, __HIP_MEMORY_SCOPE_AGENT);
                    __hip_atomic_store(&r[2], w2, __ATOMIC_RELAXED, __HIP_MEMORY_SCOPE_AGENT);
                }
            }
        }
        return;
    }

    if (wid == NCW + 1) {
        // ---- POLLER WAVE: per batch, poll 32 records, reduce, deliver -----
        for (int t = 1; t < NSAMP; ++t) {
            const u64 t2 = (u64)(((t >> 1) + 1) & 3);
            #pragma unroll
            for (int xb = 0; xb < KB; ++xb) {
                u64* reg = rec + ((size_t)((t & 1) * BATCHES + (q + 8 * xb)) * GPB) * 4;
                // lanes 0..31: (w0,w1) of record lane; lanes 32..63: w2 of
                // record lane-32.
                u64* ad = (lane < 32) ? (reg + 4 * lane) : (reg + 4 * (lane - 32) + 2);
                u64 a = 0, bw = 0;
                for (;;) {
                    bool ok;
                    a = __hip_atomic_load(&ad[0], __ATOMIC_RELAXED, __HIP_MEMORY_SCOPE_AGENT);
                    if (lane < 32) {
                        bw = __hip_atomic_load(&ad[1], __ATOMIC_RELAXED, __HIP_MEMORY_SCOPE_AGENT);
                        ok = ((a >> 62) == t2) & ((bw >> 62) == t2);
                    } else {
                        ok = (a >> 62) == t2;
                    }
                    if (__ballot(ok) == ~0ull) break;
                    __builtin_amdgcn_s_sleep(1);
                }
                u64 w2s = __shfl(a, 32 + (lane & 31), 64);
                u64 k3 = 0ull; u32 i3 = 0xFFFFFFFFu; float x3 = 0.f, y3 = 0.f, z3 = 0.f;
                if (lane < 32) {
                    u64 w0 = a, w1 = bw, w2 = w2s;
                    k3 = (w0 & 0x3FFFFFFFFFFFFFFFull) | (((w1 >> 60) & 3ull) << 62);
                    u32 xbt = (u32)(w1 >> 28);
                    u32 ybt = (u32)(((w1 & 0xFFFFFFFull) << 4) | ((w2 >> 58) & 0xFull));
                    u32 zbt = (u32)(w2 >> 26);
                    i3 = (u32)((w2 >> 9) & 0x1FFFFu);
                    x3 = __uint_as_float(xbt); y3 = __uint_as_float(ybt); z3 = __uint_as_float(zbt);
                }
                red_step(k3, i3, x3, y3, z3, 16); red_step(k3, i3, x3, y3, z3, 8);
                red_step(k3, i3, x3, y3, z3, 4);  red_step(k3, i3, x3, y3, z3, 2);
                red_step(k3, i3, x3, y3, z3, 1);
                if (lane == 0) {
                    u32 xbt = __float_as_uint(x3), ybt = __float_as_uint(y3), zbt = __float_as_uint(z3);
                    u64 v0 = (t2 << 62) | ((u64)xbt << 30) | (u64)(ybt >> 2);
                    u64 v1 = (t2 << 62) | ((u64)(ybt & 3u) << 60) | ((u64)zbt << 28) | ((u64)i3 << 11);
                    __hip_atomic_store(&winw[xb][t & 1][0], v0, __ATOMIC_RELAXED, __HIP_MEMORY_SCOPE_WORKGROUP);
                    __hip_atomic_store(&winw[xb][t & 1][1], v1, __ATOMIC_RELAXED, __HIP_MEMORY_SCOPE_WORKGROUP);
                }
            }
        }
        return;
    }

    // ---------------- COMPUTE WAVES (0..13) --------------------------------
    const int ct = tid;   // 0..895

    // Seed indices (robust to int32 / int64 farthest_init materialization).
    int odd = 0;
    #pragma unroll
    for (int i = 1; i < 32; i += 2) odd |= seed_raw[i];
    u32 scur[KB];
    #pragma unroll
    for (int xb = 0; xb < KB; ++xb) {
        const int batch = q + 8 * xb;
        scur[xb] = (u32)((odd == 0) ? seed_raw[2 * batch] : seed_raw[batch]);
    }

    // Coords (4x4x3 f32) + running f64 min-distance (4x4) in registers
    // (overflow rides the unified AGPR file, not scratch — R6 data).
    float  px[KB][PPT], py[KB][PPT], pz[KB][PPT];
    double d[KB][PPT];
    #pragma unroll
    for (int xb = 0; xb < KB; ++xb) {
        const float* cb = coord + (size_t)(q + 8 * xb) * (NPT * 3);
        #pragma unroll
        for (int k = 0; k < PPT; ++k) {
            bool v = (k < PPT - 1) || (ct < TAILT);
            int gi = base + (v ? (k * CTH + ct) : 0);
            px[xb][k] = v ? cb[(size_t)gi * 3 + 0] : 0.f;
            py[xb][k] = v ? cb[(size_t)gi * 3 + 1] : 0.f;
            pz[xb][k] = v ? cb[(size_t)gi * 3 + 2] : 0.f;
            d[xb][k]  = v ? 1.0e10 : 0.0;   // fakes can never win argmax
        }
    }

    for (int t = 0; t < NSAMP; ++t) {
        #pragma unroll
        for (int xb = 0; xb < KB; ++xb) {
            const int batch = q + 8 * xb;
            const int pi = KB * t + xb;
            u32 cur; float cx, cy, cz;
            if (t == 0) {
                cur = scur[xb];
                const float* cb = coord + (size_t)batch * (NPT * 3);
                cx = cb[(size_t)cur * 3 + 0];
                cy = cb[(size_t)cur * 3 + 1];
                cz = cb[(size_t)cur * 3 + 2];
            } else {
                const u64 t2 = (u64)(((t >> 1) + 1) & 3);
                u64 v0, v1;
                for (;;) {   // LDS spin — poller delivers ~3 phases ahead
                    v0 = __hip_atomic_load(&winw[xb][t & 1][0], __ATOMIC_RELAXED, __HIP_MEMORY_SCOPE_WORKGROUP);
                    v1 = __hip_atomic_load(&winw[xb][t & 1][1], __ATOMIC_RELAXED, __HIP_MEMORY_SCOPE_WORKGROUP);
                    if (((v0 >> 62) == t2) & ((v1 >> 62) == t2)) break;
                }
                u32 xbt = (u32)(v0 >> 30);
                u32 ybt = (u32)(((v0 & 0x3FFFFFFFull) << 2) | ((v1 >> 60) & 3ull));
                u32 zbt = (u32)(v1 >> 28);
                cur = (u32)((v1 >> 11) & 0x1FFFFu);
                cx = __uint_as_float(xbt); cy = __uint_as_float(ybt); cz = __uint_as_float(zbt);
            }
            if (g == 0 && wid == 1 && lane == 0) {
                cent_out[batch * NSAMP + t] = (float)cur;
                size_t so = ((size_t)batch * NSAMP + t) * 3;
                samp_out[so + 0] = cx; samp_out[so + 1] = cy; samp_out[so + 2] = cz;
            }
            if (t == NSAMP - 1) continue;   // last emit needs no update/publish

            // Exact f64 update + argmax (bitwise-matches float64 numpy:
            // _rn ops forbid FMA; sum order ((dx^2+dy^2)+dz^2)).
            const double cxd = (double)cx, cyd = (double)cy, czd = (double)cz;
            double bd = -1.0; u32 bi = 0;
            #pragma unroll
            for (int k = 0; k < PPT; ++k) {
                if (k == PPT - 1 && ct >= TAILT) break;
                double dx = __dsub_rn((double)px[xb][k], cxd);
                double dy = __dsub_rn((double)py[xb][k], cyd);
                double dz = __dsub_rn((double)pz[xb][k], czd);
                double d2 = __dadd_rn(__dadd_rn(__dmul_rn(dx, dx), __dmul_rn(dy, dy)),
                                      __dmul_rn(dz, dz));
                double nd = fmin(d[xb][k], d2);
                d[xb][k] = nd;
                bool gt = nd > bd;   // strict > keeps smallest k (= smallest idx)
                bd = gt ? nd : bd;
                bi = gt ? (u32)(base + k * CTH + ct) : bi;
            }
            u64 key = (u64)__double_as_longlong(bd);

            // Lean wave butterfly; the unique winner lane (distinct bi values)
            // recovers its coords and deposits.
            u64 wk = key; u32 wi = bi;
            red_ki(wk, wi, 32); red_ki(wk, wi, 16); red_ki(wk, wi, 8);
            red_ki(wk, wi, 4);  red_ki(wk, wi, 2);  red_ki(wk, wi, 1);
            if (wi == bi) {
                float bx = px[xb][0], by = py[xb][0], bz = pz[xb][0];
                #pragma unroll
                for (int k = 1; k < PPT; ++k) {
                    bool m = (bi == (u32)(base + k * CTH + ct));
                    bx = m ? px[xb][k] : bx;
                    by = m ? py[xb][k] : by;
                    bz = m ? pz[xb][k] : bz;
                }
                pkey[pi & 3][wid] = wk; pidx[pi & 3][wid] = wi;
                pxs[pi & 3][wid] = bx; pys[pi & 3][wid] = by; pzs[pi & 3][wid] = bz;
            }
            // Signal arrival; NO wait — publisher wave handles reduce+publish.
            if (lane == 0)
                __hip_atomic_fetch_add(&sbar[pi & 7], 1u, __ATOMIC_RELEASE, __HIP_MEMORY_SCOPE_WORKGROUP);
        }
    }
}

extern "C" void kernel_launch(void* const* d_in, const int* in_sizes, int n_in,
                              void* d_out, int out_size, void* d_ws, size_t ws_size,
                              hipStream_t stream)
{
    const float* coord = (const float*)d_in[0];
    const int*   seed  = (const int*)d_in[1];
    float* out = (float*)d_out;
    u64* rec = (u64*)d_ws;

    hipMemsetAsync(d_ws, 0, WS_BYTES, stream);
    fps_kernel<<<dim3(NQUAD * GPB), dim3(TPB), 0, stream>>>(coord, seed, out, rec);
}